// Round 8
// baseline (553.911 us; speedup 1.0000x reference)
//
#include <hip/hip_runtime.h>
#include <hip/hip_bf16.h>
#include <math.h>

typedef __hip_bfloat16 bf16;
typedef __bf16 bf16x8 __attribute__((ext_vector_type(8)));
typedef float f32x4 __attribute__((ext_vector_type(4)));
typedef unsigned short u16;
typedef u16 u16x8 __attribute__((ext_vector_type(8)));

#define NB 4096          // batch rows
#define DM 768           // model dim

__device__ __forceinline__ float cvt(float x){ return x; }
__device__ __forceinline__ float cvt(bf16 x){ return __bfloat162float(x); }
__device__ __forceinline__ void stv(float* p, float v){ *p = v; }
__device__ __forceinline__ void stv(bf16* p, float v){ *p = __float2bfloat16(v); }

__device__ __forceinline__ float gelu_f(float x){
    return 0.5f * x * (1.0f + erff(x * 0.70710678118654752440f));
}
__device__ __forceinline__ float sigmoid_f(float x){
    return 1.0f / (1.0f + __expf(-x));
}

__device__ __forceinline__ void async_copy16(const void* g, void* l){
    __builtin_amdgcn_global_load_lds((const __attribute__((address_space(1))) void*)g,
                                     (__attribute__((address_space(3))) void*)l, 16, 0, 0);
}

// ---------------------------------------------------------------------------
// Flat multi-job MFMA GEMM (proven 2-barrier 128x128 structure -- frozen).
// R1-R4: 256x256 8-phase kernel unreachable (toolchain register budgeting).
// R5/R6 (XCD swizzle, T1): chunked iff nx <= 16 (footprint arithmetic,
//   verified both directions on hardware).
// R7: QK-concat J5 (N=1536), act=5 gate-combine fusion, cvt merge. Counters
//   showed ld=1536 J6 operands cost ~3us (93.4 vs 90.5, FETCH flat).
// R8: (1) split-C store: merged QK job writes compact Q (cols<768, ld=768)
//   and K (cols>=768 -> C2, ld=768) buffers -> J6 back to its measured-best
//   compact-operand config. (2) classifier fused into J9 store phase:
//   act=5 + cw computes 3 partial row-dots (width-16 shfl reduce, the rs
//   pattern), writes [dir][6][NB][3] partials, SKIPS the C store (v had no
//   other consumer); tiny cls_fin does 12-partial sum + bias + softmax3.
//
// Per job: C = act((A @ Bm^T + b0) * alpha * gv + b1)
// act: 0 none, 1 gelu, 2 sigmoid, 3 relu, 4 exp, 5 store-phase
//      sigmoid(x)*aux[row,col]*sv[col] (acc-loop applies affine only).
// rs != nullptr: block (gx,gy) writes its 128 per-row tile sums to
// rs[gx*M + row] (exactly-once, no atomics).
// C2 != nullptr (trans==0 only): cols >= N/2 stored to C2, both ld = N/2.
// cw != nullptr (act==5 only): partial class-dots to rs3, C store skipped.
// A: (M,ldA) bf16 cols [0,K). Bm: (N,ldB) bf16 (B^T layout) cols [0,K).
// M%128==0, N%128==0, K%64==0. trans=1: store C^T into (N,M).
// ---------------------------------------------------------------------------
#define MAXJ 8
struct Job {
    const bf16* A; const bf16* B; bf16* C; bf16* C2;
    const float* b0; const float* gv; const float* b1;
    float* rs;
    const bf16* aux; const float* sv;
    const float* cw; float* rs3;
    int M, N, K, ldA, ldB, act, trans, blk0, nx, nb;
    float alpha;
};
struct Jobs { Job j[MAXJ]; int nj; };

__global__ __launch_bounds__(256) void mgemm_k(Jobs jb)
{
    int z = 0;
    #pragma unroll
    for (int i = 1; i < MAXJ; ++i)
        if (i < jb.nj && (int)blockIdx.x >= jb.j[i].blk0) z = i;
    const Job& J = jb.j[z];
    const bf16* __restrict__ A  = J.A;
    const bf16* __restrict__ Bm = J.B;
    bf16* __restrict__ C        = J.C;
    const int bx0 = (int)blockIdx.x - J.blk0;
    // XCD-aware chunked swizzle -- narrow jobs only (nx<=16; see header).
    int bx = bx0;
    if (J.nx <= 16 && (J.nb & 7) == 0){ const int cpx = J.nb >> 3; bx = (bx0 & 7) * cpx + (bx0 >> 3); }
    const int gx = bx % J.nx;
    const int gy = bx / J.nx;
    const int M = J.M, N = J.N, K = J.K, ldA = J.ldA, ldB = J.ldB;

    // staging: A = smem[0 .. 8191] (128x64), B = smem[8192 .. 16383]
    // epilogue: 128x136 bf16 tile = 17408 elems
    __shared__ __align__(16) bf16 smem[17408];
    const int tid  = threadIdx.x;
    const int wave = tid >> 6;
    const int lane = tid & 63;
    const int row0 = gy * 128;
    const int col0 = gx * 128;
    const int wrow = (wave & 1) * 64;
    const int wcol = (wave >> 1) * 64;
    const int fl   = lane & 15;
    const int q    = lane >> 4;

    // staging: per instr a wave stages 8 rows x 64 cols (1 KiB).
    // phys chunk (lane&7) at row r holds logical chunk (lane&7)^(r&7).
    const int sr8 = lane >> 3;
    const int sc8 = (((lane & 7) ^ sr8)) * 8;
    const bf16* pA = A  + (size_t)(row0 + wave * 32 + sr8) * ldA + sc8;
    const bf16* pB = Bm + (size_t)(col0 + wave * 32 + sr8) * ldB + sc8;
    bf16* ldsA = &smem[(wave * 32) * 64];
    bf16* ldsB = &smem[8192 + (wave * 32) * 64];

    f32x4 acc[4][4] = {};
    for (int k0 = 0; k0 < K; k0 += 64){
        #pragma unroll
        for (int i = 0; i < 4; ++i){
            async_copy16(pA + (size_t)(i * 8) * ldA, ldsA + i * 512);
            async_copy16(pB + (size_t)(i * 8) * ldB, ldsB + i * 512);
        }
        pA += 64; pB += 64;
        __syncthreads();
        #pragma unroll
        for (int ks = 0; ks < 2; ++ks){
            bf16x8 af[4], bfv[4];
            #pragma unroll
            for (int i = 0; i < 4; ++i){
                const int ra = wrow + i * 16 + fl;
                const int rb = wcol + i * 16 + fl;
                const int ca = ((ks * 4 + q) ^ (ra & 7)) * 8;
                const int cb = ((ks * 4 + q) ^ (rb & 7)) * 8;
                af[i]  = *(const bf16x8*)&smem[ra * 64 + ca];
                bfv[i] = *(const bf16x8*)&smem[8192 + rb * 64 + cb];
            }
            #pragma unroll
            for (int mi = 0; mi < 4; ++mi)
                #pragma unroll
                for (int ni = 0; ni < 4; ++ni)
                    acc[mi][ni] = __builtin_amdgcn_mfma_f32_16x16x32_bf16(af[mi], bfv[ni], acc[mi][ni], 0, 0, 0);
        }
        __syncthreads();
    }

    // epilogue: C/D layout col = lane&15, row = q*4 + reg (verified)
    // stage to LDS (padded ld=136), then block-wide 256 B coalesced stores.
    constexpr int ELD = 136;
    #pragma unroll
    for (int ni = 0; ni < 4; ++ni){
        const int col = col0 + wcol + ni * 16 + fl;
        const float b0 = J.b0 ? J.b0[col] : 0.f;
        const float gm = (J.gv ? J.gv[col] : 1.f) * J.alpha;
        const float b1 = J.b1 ? J.b1[col] : 0.f;
        const int lcol = wcol + ni * 16 + fl;
        #pragma unroll
        for (int mi = 0; mi < 4; ++mi){
            const int lrow = wrow + mi * 16 + q * 4;
            #pragma unroll
            for (int r = 0; r < 4; ++r){
                float v = (acc[mi][ni][r] + b0) * gm + b1;
                if      (J.act == 1) v = gelu_f(v);
                else if (J.act == 2) v = sigmoid_f(v);
                else if (J.act == 3) v = fmaxf(v, 0.f);
                else if (J.act == 4) v = __expf(v);
                // act==5: affine only here; sigmoid*aux*sv applied in store phase
                if (J.trans) smem[(size_t)lcol * ELD + lrow + r] = __float2bfloat16(v);
                else         smem[(size_t)(lrow + r) * ELD + lcol] = __float2bfloat16(v);
            }
        }
    }
    __syncthreads();
    // split-C routing (trans==0 only): cols >= N/2 go to C2, both ld = N/2.
    bf16* Cd = C; int ccol0 = col0; int ldC = N;
    if (J.C2){ ldC = N >> 1; if (col0 >= ldC){ Cd = J.C2; ccol0 = col0 - ldC; } }
    const int erow = tid >> 4;         // 0..15
    const int ecol = (tid & 15) * 8;   // element offset, 16 B
    #pragma unroll
    for (int p = 0; p < 8; ++p){
        const int row = p * 16 + erow;
        u16x8 uv = *(const u16x8*)&smem[row * ELD + ecol];
        if (J.act == 5){
            // gate-combine fusion: v = sigmoid(logit) * aux[row,col] * sv[col]
            const u16x8 av = *(const u16x8*)((const u16*)J.aux + (size_t)(row0 + row) * N + col0 + ecol);
            float vv[8];
            #pragma unroll
            for (int j = 0; j < 8; ++j){
                const float g = __uint_as_float((unsigned)uv[j] << 16);
                const float a = __uint_as_float((unsigned)av[j] << 16);
                vv[j] = sigmoid_f(g) * a * J.sv[col0 + ecol + j];
                uv[j] = __bfloat16_as_ushort(__float2bfloat16(vv[j]));
            }
            if (J.cw){
                // fused classifier partials: 3 row-dots over this 128-col chunk
                float s0 = 0.f, s1 = 0.f, s2 = 0.f;
                #pragma unroll
                for (int j = 0; j < 8; ++j){
                    const int c = col0 + ecol + j;
                    s0 = fmaf(vv[j], J.cw[c],          s0);
                    s1 = fmaf(vv[j], J.cw[DM + c],     s1);
                    s2 = fmaf(vv[j], J.cw[2 * DM + c], s2);
                }
                s0 += __shfl_down(s0, 8, 16); s1 += __shfl_down(s1, 8, 16); s2 += __shfl_down(s2, 8, 16);
                s0 += __shfl_down(s0, 4, 16); s1 += __shfl_down(s1, 4, 16); s2 += __shfl_down(s2, 4, 16);
                s0 += __shfl_down(s0, 2, 16); s1 += __shfl_down(s1, 2, 16); s2 += __shfl_down(s2, 2, 16);
                s0 += __shfl_down(s0, 1, 16); s1 += __shfl_down(s1, 1, 16); s2 += __shfl_down(s2, 1, 16);
                if ((tid & 15) == 0){
                    float* d = J.rs3 + ((size_t)gx * M + row0 + row) * 3;
                    d[0] = s0; d[1] = s1; d[2] = s2;     // exactly-once, no atomic
                }
            }
        }
        if (!(J.act == 5 && J.cw)){          // fused-classifier jobs skip the C store
            if (J.trans) *(u16x8*)&C[(size_t)(col0 + row) * M + row0 + ecol] = uv;
            else         *(u16x8*)&Cd[(size_t)(row0 + row) * ldC + ccol0 + ecol] = uv;
        }
        if (J.rs){
            float s = 0.f;
            #pragma unroll
            for (int j = 0; j < 8; ++j) s += __uint_as_float((unsigned)uv[j] << 16);
            s += __shfl_down(s, 8, 16);
            s += __shfl_down(s, 4, 16);
            s += __shfl_down(s, 2, 16);
            s += __shfl_down(s, 1, 16);
            if ((tid & 15) == 0) J.rs[(size_t)gx * M + row0 + row] = s;   // exactly-once, no atomic
        }
    }
}

// Reduce 32 per-chunk partials per row into the softmax denominator.
// part layout: [2 dirs][32 chunks][NB rows]; l: [2][NB].
__global__ __launch_bounds__(256) void denom_k(const float* __restrict__ part, float* __restrict__ l)
{
    const int t = blockIdx.x * 256 + threadIdx.x;     // 0 .. 2*NB-1
    if (t >= 2 * NB) return;
    const int dir = t >> 12, row = t & (NB - 1);
    const float* p = part + (size_t)dir * 32 * NB + row;
    float s = 0.f;
    #pragma unroll
    for (int c = 0; c < 32; ++c) s += p[(size_t)c * NB];
    l[t] = s;
}

// Batched fp32 -> bf16 conversion + (merged) conv-weight extract + QK bias concat
#define NCVT 14
struct CvtDesc { const float* s[NCVT]; bf16* d[NCVT]; int n[NCVT]; };
__global__ __launch_bounds__(256) void cvt_k(CvtDesc cd,
    const float* __restrict__ w1, const float* __restrict__ saw,
    bf16* __restrict__ w1c, float* __restrict__ sac,
    const float* __restrict__ bq, const float* __restrict__ bk,
    float* __restrict__ qkb)
{
    const int e = blockIdx.y;
    if (e == NCVT){
        const int idx = blockIdx.x * 256 + threadIdx.x;
        if (idx < 384 * 768){
            const int oc = idx / 768, ic = idx % 768;
            w1c[idx] = __float2bfloat16(w1[(size_t)oc * 6912 + (size_t)ic * 9 + 4]);
        }
        if (idx < 384) sac[idx] = saw[(size_t)idx * 49 + 24];
        if (idx < 768)                   qkb[idx] = bq[idx];
        else if (idx < 1536)             qkb[idx] = bk[idx - 768];
        return;
    }
    const int base = (blockIdx.x * 256 + threadIdx.x) * 4;
    if (base >= cd.n[e]) return;
    const float4 v = *(const float4*)(cd.s[e] + base);
    union { bf16 h[4]; unsigned long long u; } o;
    o.h[0] = __float2bfloat16(v.x);
    o.h[1] = __float2bfloat16(v.y);
    o.h[2] = __float2bfloat16(v.z);
    o.h[3] = __float2bfloat16(v.w);
    *(unsigned long long*)(cd.d[e] + base) = o.u;
}

// Fused FDA tail: ca1 -> ca2 -> x2 -> sa -> x3 -> dec -> x4, in place
__global__ __launch_bounds__(128) void fda_fused_k(
    bf16* __restrict__ x, const float* __restrict__ wc1, const float* __restrict__ wc2,
    const float* __restrict__ sac, const float* __restrict__ sab,
    const float* __restrict__ decw, const float* __restrict__ decb,
    const float* __restrict__ sigma)
{
    __shared__ float xs[384];
    __shared__ float ca1s[24];
    __shared__ float red[128];
    const int b = blockIdx.x;
    const int tid = threadIdx.x;
    bf16* xr = x + (size_t)b * 384;
    #pragma unroll
    for (int i = 0; i < 3; ++i) xs[tid + i * 128] = cvt(xr[tid + i * 128]);
    __syncthreads();
    if (tid < 96){
        const int o = tid >> 2, sub = tid & 3;
        const float* w = wc1 + (size_t)o * 384 + sub * 96;
        float p = 0.f;
        #pragma unroll 8
        for (int k = 0; k < 96; ++k) p = fmaf(xs[sub * 96 + k], w[k], p);
        p += __shfl_down(p, 1, 64);
        p += __shfl_down(p, 2, 64);
        if (sub == 0) ca1s[o] = gelu_f(p);
    }
    __syncthreads();
    float x2[3];
    float p = 0.f;
    #pragma unroll
    for (int i = 0; i < 3; ++i){
        const int c = tid + i * 128;
        float s = 0.f;
        const float* w = wc2 + (size_t)c * 24;
        #pragma unroll
        for (int k = 0; k < 24; ++k) s = fmaf(ca1s[k], w[k], s);
        const float v = xs[c] * sigmoid_f(s);
        x2[i] = v;
        p += v * sac[c];
    }
    red[tid] = p; __syncthreads();
    for (int s = 64; s > 0; s >>= 1){ if (tid < s) red[tid] += red[tid + s]; __syncthreads(); }
    const float sa = sigmoid_f(red[0] + sab[0]);
    __syncthreads();
    float qq = 0.f;
    #pragma unroll
    for (int i = 0; i < 3; ++i){
        const int c = tid + i * 128;
        x2[i] *= sa;
        qq += x2[i] * decw[c];
    }
    red[tid] = qq; __syncthreads();
    for (int s = 64; s > 0; s >>= 1){ if (tid < s) red[tid] += red[tid + s]; __syncthreads(); }
    const float xg = gelu_f(red[0] + decb[0]);
    #pragma unroll
    for (int i = 0; i < 3; ++i){
        const int c = tid + i * 128;
        const float sg = sigma[c];
        stv(&xr[c], x2[i] + sg * (x2[i] - xg));
    }
}

// o1 = (a+b)/l1[row] ; o2 = (c+d)/l2[row]  (split-K reduce + softmax denom)
__global__ __launch_bounds__(256) void reduce2_k(
    const bf16* __restrict__ a, const bf16* __restrict__ b, bf16* __restrict__ o1,
    const float* __restrict__ l1,
    const bf16* __restrict__ c, const bf16* __restrict__ d, bf16* __restrict__ o2,
    const float* __restrict__ l2)
{
    const size_t i = ((size_t)blockIdx.x * 256 + threadIdx.x) * 8;
    if (i >= (size_t)NB * DM) return;
    const int row = (int)(i / DM);     // 8-elem chunk never crosses a row (768 % 8 == 0)
    const float inv1 = 1.0f / l1[row];
    const float inv2 = 1.0f / l2[row];
    u16x8 ua = *(const u16x8*)((const u16*)a + i);
    u16x8 ub = *(const u16x8*)((const u16*)b + i);
    u16x8 uc = *(const u16x8*)((const u16*)c + i);
    u16x8 ud = *(const u16x8*)((const u16*)d + i);
    u16x8 r1, r2;
    #pragma unroll
    for (int j = 0; j < 8; ++j){
        const float s1 = (__uint_as_float((unsigned)ua[j] << 16) + __uint_as_float((unsigned)ub[j] << 16)) * inv1;
        const float s2 = (__uint_as_float((unsigned)uc[j] << 16) + __uint_as_float((unsigned)ud[j] << 16)) * inv2;
        r1[j] = __bfloat16_as_ushort(__float2bfloat16(s1));
        r2[j] = __bfloat16_as_ushort(__float2bfloat16(s2));
    }
    *(u16x8*)((u16*)o1 + i) = r1;
    *(u16x8*)((u16*)o2 + i) = r2;
}

// Final classifier: sum 12 partial logit chunks (2 dirs x 6 col-chunks) + bias,
// softmax(3). part2 layout: [dir*6+g][NB][3].
__global__ __launch_bounds__(256) void cls_fin_k(
    const float* __restrict__ p2, const float* __restrict__ bias, float* __restrict__ out)
{
    const int row = blockIdx.x * 256 + threadIdx.x;
    if (row >= NB) return;
    float l0 = bias[0], l1 = bias[1], l2 = bias[2];
    #pragma unroll
    for (int g = 0; g < 12; ++g){
        const float* q = p2 + ((size_t)g * NB + row) * 3;
        l0 += q[0]; l1 += q[1]; l2 += q[2];
    }
    const float mx = fmaxf(l0, fmaxf(l1, l2));
    const float e0 = __expf(l0 - mx), e1 = __expf(l1 - mx), e2 = __expf(l2 - mx);
    const float inv = 1.f / (e0 + e1 + e2);
    out[(size_t)row * 3 + 0] = e0 * inv;
    out[(size_t)row * 3 + 1] = e1 * inv;
    out[(size_t)row * 3 + 2] = e2 * inv;
}

extern "C" void kernel_launch(void* const* d_in, const int* in_sizes, int n_in,
                              void* d_out, int out_size, void* d_ws, size_t ws_size,
                              hipStream_t stream)
{
    const float* text   = (const float*)d_in[0];
    const float* image  = (const float*)d_in[1];
    const float* tl_w   = (const float*)d_in[2];
    const float* tl_b   = (const float*)d_in[3];
    const float* il_w   = (const float*)d_in[4];
    const float* il_b   = (const float*)d_in[5];
    const float* sda_wv = (const float*)d_in[10];
    const float* sda_bv = (const float*)d_in[11];
    const float* sda_wo = (const float*)d_in[12];
    const float* sda_bo = (const float*)d_in[13];
    const float* fda_w1 = (const float*)d_in[14];
    const float* fda_b1 = (const float*)d_in[15];
    const float* bn1_g  = (const float*)d_in[16];
    const float* bn1_b  = (const float*)d_in[17];
    const float* ca_w1  = (const float*)d_in[18];
    const float* ca_w2  = (const float*)d_in[19];
    const float* sa_w   = (const float*)d_in[20];
    const float* sa_b   = (const float*)d_in[21];
    const float* dec_w  = (const float*)d_in[22];
    const float* dec_b  = (const float*)d_in[23];
    const float* sigma  = (const float*)d_in[24];
    const float* fda_wf = (const float*)d_in[25];
    const float* fda_bf = (const float*)d_in[26];
    const float* bn2_g  = (const float*)d_in[27];
    const float* bn2_b  = (const float*)d_in[28];
    const float* dmi_wq = (const float*)d_in[29];
    const float* dmi_bq = (const float*)d_in[30];
    const float* dmi_wk = (const float*)d_in[31];
    const float* dmi_bk = (const float*)d_in[32];
    const float* dmi_wv = (const float*)d_in[33];
    const float* dmi_bv = (const float*)d_in[34];
    const float* tg_w1  = (const float*)d_in[35];
    const float* tg_b1  = (const float*)d_in[36];
    const float* tg_w2  = (const float*)d_in[37];
    const float* tg_b2  = (const float*)d_in[38];
    const float* ig_w1  = (const float*)d_in[39];
    const float* ig_b1  = (const float*)d_in[40];
    const float* ig_w2  = (const float*)d_in[41];
    const float* ig_b2  = (const float*)d_in[42];
    const float* t_scale= (const float*)d_in[43];
    const float* i_scale= (const float*)d_in[44];
    const float* cls_w  = (const float*)d_in[45];
    const float* cls_b  = (const float*)d_in[46];
    float* out = (float*)d_out;

    // ---- workspace (~130 MB) ----
    char* base = (char*)d_ws;
    auto alloc = [&](size_t bytes){ void* p = (void*)base; base += (bytes + 255) & ~(size_t)255; return p; };
    const size_t SLOT = (size_t)NB * DM;
    const size_t W768 = (size_t)768 * 768;
    bf16* tl_wb   = (bf16*)alloc(W768 * 2);
    bf16* il_wb   = (bf16*)alloc(W768 * 2);
    bf16* sda_wvb = (bf16*)alloc((size_t)512 * 768 * 2);
    bf16* sda_wob = (bf16*)alloc((size_t)768 * 512 * 2);
    bf16* fda_wfb = (bf16*)alloc((size_t)768 * 384 * 2);
    // dmi_wqb and dmi_wkb MUST stay adjacent: together they form Wqk (1536x768)
    // for the merged J5 jobs. (All preceding alloc sizes are 256-multiples, so
    // alloc introduces no padding between them.)
    bf16* dmi_wqb = (bf16*)alloc(W768 * 2);
    bf16* dmi_wkb = (bf16*)alloc(W768 * 2);
    bf16* dmi_wvb = (bf16*)alloc(W768 * 2);
    bf16* tg_w1b  = (bf16*)alloc(W768 * 2);
    bf16* tg_w2b  = (bf16*)alloc(W768 * 2);
    bf16* ig_w1b  = (bf16*)alloc(W768 * 2);
    bf16* ig_w2b  = (bf16*)alloc(W768 * 2);
    bf16* w1c     = (bf16*)alloc((size_t)384 * 768 * 2);
    float* sac    = (float*)alloc(1536 * 4);
    float* qkb    = (float*)alloc(1536 * 4);                 // [bq; bk] concat
    float* lbuf   = (float*)alloc(2 * NB * 4);               // final denominators [2][NB]
    float* part   = (float*)alloc((size_t)2 * 32 * NB * 4);  // per-chunk partials [2][32][NB], 1 MB
    float* part2  = (float*)alloc((size_t)12 * NB * 3 * 4);  // classifier partials [12][NB][3]
    bf16* SL[8];
    for (int i = 0; i < 8; ++i) SL[i] = (bf16*)alloc(SLOT * 2);
    bf16* SC1 = (bf16*)alloc((size_t)NB * NB * 2);
    bf16* SC2 = (bf16*)alloc((size_t)NB * NB * 2);

    const float bnscale = 1.0f / sqrtf(1.0f + 1e-5f);
    const float iscale  = 1.0f / sqrtf(768.0f);
    const dim3 blk(256);

    struct JB {
        Jobs jb; int blocks;
        void add(const bf16* A, const bf16* B, bf16* C, int M, int N, int K, int ldA, int ldB,
                 const float* b0, float al, const float* gv, const float* b1, int act, int trans,
                 float* rs = nullptr, const bf16* aux = nullptr, const float* sv = nullptr,
                 bf16* C2 = nullptr, const float* cw = nullptr, float* rs3 = nullptr){
            Job& j = jb.j[jb.nj++];
            j.A=A; j.B=B; j.C=C; j.C2=C2; j.b0=b0; j.gv=gv; j.b1=b1; j.rs=rs; j.aux=aux; j.sv=sv;
            j.cw=cw; j.rs3=rs3;
            j.M=M; j.N=N; j.K=K; j.ldA=ldA; j.ldB=ldB; j.act=act; j.trans=trans;
            j.alpha=al; j.blk0=blocks; j.nx=N/128; j.nb=(N/128)*(M/128);
            blocks += (N/128)*(M/128);
        }
    };
    auto launch = [&](JB& b){ mgemm_k<<<dim3(b.blocks), blk, 0, stream>>>(b.jb); };

    // fp32 -> bf16 staging (+ merged conv-weight extract + QK-bias concat)
    CvtDesc cd;
    const float* srcs[NCVT] = {text, image, tl_w, il_w, sda_wv, sda_wo, fda_wf,
                               dmi_wq, dmi_wk, dmi_wv, tg_w1, tg_w2, ig_w1, ig_w2};
    bf16* dsts[NCVT] = {SL[0], SL[1], tl_wb, il_wb, sda_wvb, sda_wob, fda_wfb,
                        dmi_wqb, dmi_wkb, dmi_wvb, tg_w1b, tg_w2b, ig_w1b, ig_w2b};
    int   lens[NCVT] = {(int)SLOT, (int)SLOT, (int)W768, (int)W768, 512*768, 768*512, 768*384,
                        (int)W768, (int)W768, (int)W768, (int)W768, (int)W768, (int)W768, (int)W768};
    for (int i = 0; i < NCVT; ++i){ cd.s[i] = srcs[i]; cd.d[i] = dsts[i]; cd.n[i] = lens[i]; }
    cvt_k<<<dim3((int)(SLOT / 1024), NCVT + 1), blk, 0, stream>>>(cd, fda_w1, sa_w, w1c, sac,
                                                                  dmi_bq, dmi_bk, qkb);

    // J1: t0 = gelu(text@tl^T) -> SL2 ; im0 = gelu(image@il^T) -> SL3
    { JB b{}; b.add(SL[0], tl_wb, SL[2], NB, DM, DM, DM, DM, tl_b, 1.f, nullptr, nullptr, 1, 0);
              b.add(SL[1], il_wb, SL[3], NB, DM, DM, DM, DM, il_b, 1.f, nullptr, nullptr, 1, 0); launch(b); }
    // J2: wv = t0@wv^T -> SL0 (N=512) ; x1 = conv1(im0) -> SL1 (N=384)
    { JB b{}; b.add(SL[2], sda_wvb, SL[0], NB, 512, DM, DM, DM, sda_bv, 1.f, nullptr, nullptr, 0, 0);
              b.add(SL[3], w1c,     SL[1], NB, 384, DM, DM, DM, fda_b1, bnscale, bn1_g, bn1_b, 1, 0); launch(b); }
    // fused FDA tail (in place on SL1)
    fda_fused_k<<<dim3(NB), dim3(128), 0, stream>>>(SL[1], ca_w1, ca_w2, sac, sa_b, dec_w, dec_b, sigma);
    // J34 (batched): t1 = wv@wo^T -> SL4 (K=512) ; im1 = gelu((x4@wf^T+bf)*bn2) -> SL5 (K=384)
    { JB b{}; b.add(SL[0], sda_wob, SL[4], NB, DM, 512, 512, 512, sda_bo, 1.f, nullptr, nullptr, 0, 0);
              b.add(SL[1], fda_wfb, SL[5], NB, DM, 384, 384, 384, fda_bf, bnscale, bn2_g, bn2_b, 1, 0); launch(b); }

    // J5: merged QK (N=1536, Wqk = [wq;wk]) with SPLIT-C compact outputs:
    //   t-dir:  Q_t -> SL0 (ld 768), K_t -> SL1 (ld 768)
    //   im-dir: Q_im -> SL2,         K_im -> SL3
    // plus V^T jobs.
    { JB b{};
      b.add(SL[4], dmi_wqb, SL[0], NB, 1536, DM, DM, DM, qkb,    1.f, nullptr, nullptr, 0, 0,
            nullptr, nullptr, nullptr, SL[1]);
      b.add(SL[5], dmi_wqb, SL[2], NB, 1536, DM, DM, DM, qkb,    1.f, nullptr, nullptr, 0, 0,
            nullptr, nullptr, nullptr, SL[3]);
      b.add(SL[5], dmi_wvb, SL[6], NB, DM,   DM, DM, DM, dmi_bv, 1.f, nullptr, nullptr, 0, 1);   // V_im^T
      b.add(SL[4], dmi_wvb, SL[7], NB, DM,   DM, DM, DM, dmi_bv, 1.f, nullptr, nullptr, 0, 1);   // V_t^T
      launch(b); }
    // J6: scores (compact ld=768 operands) with fused exp + per-block partial row sums
    { JB b{}; b.add(SL[0], SL[3], SC1, NB, NB, DM, DM, DM, nullptr, iscale, nullptr, nullptr, 4, 0, part);
              b.add(SL[2], SL[1], SC2, NB, NB, DM, DM, DM, nullptr, iscale, nullptr, nullptr, 4, 0, part + 32 * NB); launch(b); }
    // reduce partials -> lbuf
    denom_k<<<dim3((2 * NB + 255) / 256), blk, 0, stream>>>(part, lbuf);
    // J7: PV split-K=2 x 2 dirs (4 jobs, 768 blocks) on unnormalized exp-scores
    { JB b{};
      b.add(SC1,        SL[6],        SL[0], NB, DM, 2048, NB, NB, nullptr, 1.f, nullptr, nullptr, 0, 0);
      b.add(SC1 + 2048, SL[6] + 2048, SL[1], NB, DM, 2048, NB, NB, nullptr, 1.f, nullptr, nullptr, 0, 0);
      b.add(SC2,        SL[7],        SL[2], NB, DM, 2048, NB, NB, nullptr, 1.f, nullptr, nullptr, 0, 0);
      b.add(SC2 + 2048, SL[7] + 2048, SL[3], NB, DM, 2048, NB, NB, nullptr, 1.f, nullptr, nullptr, 0, 0);
      launch(b); }
    // a1 = (SL0+SL1)/l1 -> SL4 ; a2 = (SL2+SL3)/l2 -> SL5
    reduce2_k<<<dim3((int)(SLOT / 2048)), blk, 0, stream>>>(SL[0], SL[1], SL[4], lbuf,
                                                           SL[2], SL[3], SL[5], lbuf + NB);
    // J8: gate hidden (relu)
    { JB b{}; b.add(SL[4], tg_w1b, SL[0], NB, DM, DM, DM, DM, tg_b1, 1.f, nullptr, nullptr, 3, 0);
              b.add(SL[5], ig_w1b, SL[1], NB, DM, DM, DM, DM, ig_b1, 1.f, nullptr, nullptr, 3, 0); launch(b); }
    // J9: gate out + fused combine (act=5) + FUSED CLASSIFIER PARTIALS
    //     (v = sigmoid(logit)*a*scale; partial dots -> part2; no C store)
    { JB b{}; b.add(SL[0], tg_w2b, SL[3], NB, DM, DM, DM, DM, tg_b2, 1.f, nullptr, nullptr, 5, 0,
                    nullptr, SL[4], t_scale, nullptr, cls_w, part2);
              b.add(SL[1], ig_w2b, SL[6], NB, DM, DM, DM, DM, ig_b2, 1.f, nullptr, nullptr, 5, 0,
                    nullptr, SL[5], i_scale, nullptr, cls_w, part2 + (size_t)6 * NB * 3); launch(b); }
    // final: 12-partial sum + bias + softmax(3)
    cls_fin_k<<<dim3((NB + 255) / 256), blk, 0, stream>>>(part2, cls_b, out);
}

// Round 9
// 542.904 us; speedup vs baseline: 1.0203x; 1.0203x over previous
//
#include <hip/hip_runtime.h>
#include <hip/hip_bf16.h>
#include <math.h>

typedef __hip_bfloat16 bf16;
typedef __bf16 bf16x8 __attribute__((ext_vector_type(8)));
typedef float f32x4 __attribute__((ext_vector_type(4)));
typedef unsigned short u16;
typedef u16 u16x8 __attribute__((ext_vector_type(8)));

#define NB 4096          // batch rows
#define DM 768           // model dim

__device__ __forceinline__ float cvt(float x){ return x; }
__device__ __forceinline__ float cvt(bf16 x){ return __bfloat162float(x); }
__device__ __forceinline__ void stv(float* p, float v){ *p = v; }
__device__ __forceinline__ void stv(bf16* p, float v){ *p = __float2bfloat16(v); }

__device__ __forceinline__ float gelu_f(float x){
    return 0.5f * x * (1.0f + erff(x * 0.70710678118654752440f));
}
__device__ __forceinline__ float sigmoid_f(float x){
    return 1.0f / (1.0f + __expf(-x));
}

__device__ __forceinline__ void async_copy16(const void* g, void* l){
    __builtin_amdgcn_global_load_lds((const __attribute__((address_space(1))) void*)g,
                                     (__attribute__((address_space(3))) void*)l, 16, 0, 0);
}

// ---------------------------------------------------------------------------
// Flat multi-job MFMA GEMM (proven 2-barrier 128x128 structure -- frozen).
// Session ledger (harness-measured):
// R1-R4: 256x256 8-phase kernel unreachable (toolchain register budgeting:
//   512-thr pinned to 128-reg cap; amdgpu_* attrs ignored; 256-thr caps at
//   256 arch VGPRs with no AGPR overflow -> spills). Do not re-attempt.
// R5/R6 (XCD swizzle, T1): chunked iff nx <= 16 (footprint arithmetic,
//   verified both directions on hardware: nx=32 chunked = B-thrash, -7%).
// R7 (BEST, 535.3us): QK-concat J5 (N=1536), act=5 gate-combine fusion
//   (removes 12MB of reads -- traffic-removing fusion WINS), cvt merge.
// R8 (REVERTED, 553.9us): (a) split-C compact J6 operands -> J6 unchanged
//   (93.7us, FETCH identical) -- R7's J6 delta was NOT operand stride, it is
//   noise-band/codegen-secondary; (b) classifier fused into J9 store phase
//   -> +18.6us total: ~192 scalar cw loads + 96 shfls per thread on J9's
//   store path cost far more than the 12-15us combine_cls kernel it
//   replaced. Lesson: epilogue fusion pays only when it REMOVES traffic,
//   not when it ADDS serial VALU work to a busy store phase.
//
// Per job: C = act((A @ Bm^T + b0) * alpha * gv + b1)
// act: 0 none, 1 gelu, 2 sigmoid, 3 relu, 4 exp, 5 store-phase
//      sigmoid(x)*aux[row,col]*sv[col] (acc-loop applies affine only).
// rs != nullptr: block (gx,gy) writes its 128 per-row tile sums to
// rs[gx*M + row] (exactly-once, no atomics).
// A: (M,ldA) bf16 cols [0,K). Bm: (N,ldB) bf16 (B^T layout) cols [0,K).
// M%128==0, N%128==0, K%64==0. trans=1: store C^T into (N,M).
// ---------------------------------------------------------------------------
#define MAXJ 8
struct Job {
    const bf16* A; const bf16* B; bf16* C;
    const float* b0; const float* gv; const float* b1;
    float* rs;
    const bf16* aux; const float* sv;
    int M, N, K, ldA, ldB, act, trans, blk0, nx, nb;
    float alpha;
};
struct Jobs { Job j[MAXJ]; int nj; };

__global__ __launch_bounds__(256) void mgemm_k(Jobs jb)
{
    int z = 0;
    #pragma unroll
    for (int i = 1; i < MAXJ; ++i)
        if (i < jb.nj && (int)blockIdx.x >= jb.j[i].blk0) z = i;
    const Job& J = jb.j[z];
    const bf16* __restrict__ A  = J.A;
    const bf16* __restrict__ Bm = J.B;
    bf16* __restrict__ C        = J.C;
    const int bx0 = (int)blockIdx.x - J.blk0;
    // XCD-aware chunked swizzle -- narrow jobs only (nx<=16; see header).
    int bx = bx0;
    if (J.nx <= 16 && (J.nb & 7) == 0){ const int cpx = J.nb >> 3; bx = (bx0 & 7) * cpx + (bx0 >> 3); }
    const int gx = bx % J.nx;
    const int gy = bx / J.nx;
    const int M = J.M, N = J.N, K = J.K, ldA = J.ldA, ldB = J.ldB;

    // staging: A = smem[0 .. 8191] (128x64), B = smem[8192 .. 16383]
    // epilogue: 128x136 bf16 tile = 17408 elems
    __shared__ __align__(16) bf16 smem[17408];
    const int tid  = threadIdx.x;
    const int wave = tid >> 6;
    const int lane = tid & 63;
    const int row0 = gy * 128;
    const int col0 = gx * 128;
    const int wrow = (wave & 1) * 64;
    const int wcol = (wave >> 1) * 64;
    const int fl   = lane & 15;
    const int q    = lane >> 4;

    // staging: per instr a wave stages 8 rows x 64 cols (1 KiB).
    // phys chunk (lane&7) at row r holds logical chunk (lane&7)^(r&7).
    const int sr8 = lane >> 3;
    const int sc8 = (((lane & 7) ^ sr8)) * 8;
    const bf16* pA = A  + (size_t)(row0 + wave * 32 + sr8) * ldA + sc8;
    const bf16* pB = Bm + (size_t)(col0 + wave * 32 + sr8) * ldB + sc8;
    bf16* ldsA = &smem[(wave * 32) * 64];
    bf16* ldsB = &smem[8192 + (wave * 32) * 64];

    f32x4 acc[4][4] = {};
    for (int k0 = 0; k0 < K; k0 += 64){
        #pragma unroll
        for (int i = 0; i < 4; ++i){
            async_copy16(pA + (size_t)(i * 8) * ldA, ldsA + i * 512);
            async_copy16(pB + (size_t)(i * 8) * ldB, ldsB + i * 512);
        }
        pA += 64; pB += 64;
        __syncthreads();
        #pragma unroll
        for (int ks = 0; ks < 2; ++ks){
            bf16x8 af[4], bfv[4];
            #pragma unroll
            for (int i = 0; i < 4; ++i){
                const int ra = wrow + i * 16 + fl;
                const int rb = wcol + i * 16 + fl;
                const int ca = ((ks * 4 + q) ^ (ra & 7)) * 8;
                const int cb = ((ks * 4 + q) ^ (rb & 7)) * 8;
                af[i]  = *(const bf16x8*)&smem[ra * 64 + ca];
                bfv[i] = *(const bf16x8*)&smem[8192 + rb * 64 + cb];
            }
            #pragma unroll
            for (int mi = 0; mi < 4; ++mi)
                #pragma unroll
                for (int ni = 0; ni < 4; ++ni)
                    acc[mi][ni] = __builtin_amdgcn_mfma_f32_16x16x32_bf16(af[mi], bfv[ni], acc[mi][ni], 0, 0, 0);
        }
        __syncthreads();
    }

    // epilogue: C/D layout col = lane&15, row = q*4 + reg (verified)
    // stage to LDS (padded ld=136), then block-wide 256 B coalesced stores.
    constexpr int ELD = 136;
    #pragma unroll
    for (int ni = 0; ni < 4; ++ni){
        const int col = col0 + wcol + ni * 16 + fl;
        const float b0 = J.b0 ? J.b0[col] : 0.f;
        const float gm = (J.gv ? J.gv[col] : 1.f) * J.alpha;
        const float b1 = J.b1 ? J.b1[col] : 0.f;
        const int lcol = wcol + ni * 16 + fl;
        #pragma unroll
        for (int mi = 0; mi < 4; ++mi){
            const int lrow = wrow + mi * 16 + q * 4;
            #pragma unroll
            for (int r = 0; r < 4; ++r){
                float v = (acc[mi][ni][r] + b0) * gm + b1;
                if      (J.act == 1) v = gelu_f(v);
                else if (J.act == 2) v = sigmoid_f(v);
                else if (J.act == 3) v = fmaxf(v, 0.f);
                else if (J.act == 4) v = __expf(v);
                // act==5: affine only here; sigmoid*aux*sv applied in store phase
                if (J.trans) smem[(size_t)lcol * ELD + lrow + r] = __float2bfloat16(v);
                else         smem[(size_t)(lrow + r) * ELD + lcol] = __float2bfloat16(v);
            }
        }
    }
    __syncthreads();
    const int erow = tid >> 4;         // 0..15
    const int ecol = (tid & 15) * 8;   // element offset, 16 B
    #pragma unroll
    for (int p = 0; p < 8; ++p){
        const int row = p * 16 + erow;
        u16x8 uv = *(const u16x8*)&smem[row * ELD + ecol];
        if (J.act == 5){
            // gate-combine fusion: v = sigmoid(logit) * aux[row,col] * sv[col]
            // (coalesced u16x8 aux load mirrors the C-store pattern; logit was
            //  bf16-staged exactly as the old standalone-gate path was.)
            const u16x8 av = *(const u16x8*)((const u16*)J.aux + (size_t)(row0 + row) * N + col0 + ecol);
            #pragma unroll
            for (int j = 0; j < 8; ++j){
                const float g = __uint_as_float((unsigned)uv[j] << 16);
                const float a = __uint_as_float((unsigned)av[j] << 16);
                const float v = sigmoid_f(g) * a * J.sv[col0 + ecol + j];
                uv[j] = __bfloat16_as_ushort(__float2bfloat16(v));
            }
        }
        if (J.trans) *(u16x8*)&C[(size_t)(col0 + row) * M + row0 + ecol] = uv;
        else         *(u16x8*)&C[(size_t)(row0 + row) * N + col0 + ecol] = uv;
        if (J.rs){
            float s = 0.f;
            #pragma unroll
            for (int j = 0; j < 8; ++j) s += __uint_as_float((unsigned)uv[j] << 16);
            s += __shfl_down(s, 8, 16);
            s += __shfl_down(s, 4, 16);
            s += __shfl_down(s, 2, 16);
            s += __shfl_down(s, 1, 16);
            if ((tid & 15) == 0) J.rs[(size_t)gx * M + row0 + row] = s;   // exactly-once, no atomic
        }
    }
}

// Reduce 32 per-chunk partials per row into the softmax denominator.
// part layout: [2 dirs][32 chunks][NB rows]; l: [2][NB].
__global__ __launch_bounds__(256) void denom_k(const float* __restrict__ part, float* __restrict__ l)
{
    const int t = blockIdx.x * 256 + threadIdx.x;     // 0 .. 2*NB-1
    if (t >= 2 * NB) return;
    const int dir = t >> 12, row = t & (NB - 1);
    const float* p = part + (size_t)dir * 32 * NB + row;
    float s = 0.f;
    #pragma unroll
    for (int c = 0; c < 32; ++c) s += p[(size_t)c * NB];
    l[t] = s;
}

// Batched fp32 -> bf16 conversion + (merged) conv-weight extract + QK bias concat
#define NCVT 14
struct CvtDesc { const float* s[NCVT]; bf16* d[NCVT]; int n[NCVT]; };
__global__ __launch_bounds__(256) void cvt_k(CvtDesc cd,
    const float* __restrict__ w1, const float* __restrict__ saw,
    bf16* __restrict__ w1c, float* __restrict__ sac,
    const float* __restrict__ bq, const float* __restrict__ bk,
    float* __restrict__ qkb)
{
    const int e = blockIdx.y;
    if (e == NCVT){
        const int idx = blockIdx.x * 256 + threadIdx.x;
        if (idx < 384 * 768){
            const int oc = idx / 768, ic = idx % 768;
            w1c[idx] = __float2bfloat16(w1[(size_t)oc * 6912 + (size_t)ic * 9 + 4]);
        }
        if (idx < 384) sac[idx] = saw[(size_t)idx * 49 + 24];
        if (idx < 768)                   qkb[idx] = bq[idx];
        else if (idx < 1536)             qkb[idx] = bk[idx - 768];
        return;
    }
    const int base = (blockIdx.x * 256 + threadIdx.x) * 4;
    if (base >= cd.n[e]) return;
    const float4 v = *(const float4*)(cd.s[e] + base);
    union { bf16 h[4]; unsigned long long u; } o;
    o.h[0] = __float2bfloat16(v.x);
    o.h[1] = __float2bfloat16(v.y);
    o.h[2] = __float2bfloat16(v.z);
    o.h[3] = __float2bfloat16(v.w);
    *(unsigned long long*)(cd.d[e] + base) = o.u;
}

// Fused FDA tail: ca1 -> ca2 -> x2 -> sa -> x3 -> dec -> x4, in place
__global__ __launch_bounds__(128) void fda_fused_k(
    bf16* __restrict__ x, const float* __restrict__ wc1, const float* __restrict__ wc2,
    const float* __restrict__ sac, const float* __restrict__ sab,
    const float* __restrict__ decw, const float* __restrict__ decb,
    const float* __restrict__ sigma)
{
    __shared__ float xs[384];
    __shared__ float ca1s[24];
    __shared__ float red[128];
    const int b = blockIdx.x;
    const int tid = threadIdx.x;
    bf16* xr = x + (size_t)b * 384;
    #pragma unroll
    for (int i = 0; i < 3; ++i) xs[tid + i * 128] = cvt(xr[tid + i * 128]);
    __syncthreads();
    if (tid < 96){
        const int o = tid >> 2, sub = tid & 3;
        const float* w = wc1 + (size_t)o * 384 + sub * 96;
        float p = 0.f;
        #pragma unroll 8
        for (int k = 0; k < 96; ++k) p = fmaf(xs[sub * 96 + k], w[k], p);
        p += __shfl_down(p, 1, 64);
        p += __shfl_down(p, 2, 64);
        if (sub == 0) ca1s[o] = gelu_f(p);
    }
    __syncthreads();
    float x2[3];
    float p = 0.f;
    #pragma unroll
    for (int i = 0; i < 3; ++i){
        const int c = tid + i * 128;
        float s = 0.f;
        const float* w = wc2 + (size_t)c * 24;
        #pragma unroll
        for (int k = 0; k < 24; ++k) s = fmaf(ca1s[k], w[k], s);
        const float v = xs[c] * sigmoid_f(s);
        x2[i] = v;
        p += v * sac[c];
    }
    red[tid] = p; __syncthreads();
    for (int s = 64; s > 0; s >>= 1){ if (tid < s) red[tid] += red[tid + s]; __syncthreads(); }
    const float sa = sigmoid_f(red[0] + sab[0]);
    __syncthreads();
    float qq = 0.f;
    #pragma unroll
    for (int i = 0; i < 3; ++i){
        const int c = tid + i * 128;
        x2[i] *= sa;
        qq += x2[i] * decw[c];
    }
    red[tid] = qq; __syncthreads();
    for (int s = 64; s > 0; s >>= 1){ if (tid < s) red[tid] += red[tid + s]; __syncthreads(); }
    const float xg = gelu_f(red[0] + decb[0]);
    #pragma unroll
    for (int i = 0; i < 3; ++i){
        const int c = tid + i * 128;
        const float sg = sigma[c];
        stv(&xr[c], x2[i] + sg * (x2[i] - xg));
    }
}

// o1 = (a+b)/l1[row] ; o2 = (c+d)/l2[row]  (split-K reduce + softmax denom)
__global__ __launch_bounds__(256) void reduce2_k(
    const bf16* __restrict__ a, const bf16* __restrict__ b, bf16* __restrict__ o1,
    const float* __restrict__ l1,
    const bf16* __restrict__ c, const bf16* __restrict__ d, bf16* __restrict__ o2,
    const float* __restrict__ l2)
{
    const size_t i = ((size_t)blockIdx.x * 256 + threadIdx.x) * 8;
    if (i >= (size_t)NB * DM) return;
    const int row = (int)(i / DM);     // 8-elem chunk never crosses a row (768 % 8 == 0)
    const float inv1 = 1.0f / l1[row];
    const float inv2 = 1.0f / l2[row];
    u16x8 ua = *(const u16x8*)((const u16*)a + i);
    u16x8 ub = *(const u16x8*)((const u16*)b + i);
    u16x8 uc = *(const u16x8*)((const u16*)c + i);
    u16x8 ud = *(const u16x8*)((const u16*)d + i);
    u16x8 r1, r2;
    #pragma unroll
    for (int j = 0; j < 8; ++j){
        const float s1 = (__uint_as_float((unsigned)ua[j] << 16) + __uint_as_float((unsigned)ub[j] << 16)) * inv1;
        const float s2 = (__uint_as_float((unsigned)uc[j] << 16) + __uint_as_float((unsigned)ud[j] << 16)) * inv2;
        r1[j] = __bfloat16_as_ushort(__float2bfloat16(s1));
        r2[j] = __bfloat16_as_ushort(__float2bfloat16(s2));
    }
    *(u16x8*)((u16*)o1 + i) = r1;
    *(u16x8*)((u16*)o2 + i) = r2;
}

// Slim classifier: logits = (v1+v2) @ w^T + bias; softmax(3).
// (gate-combine v = sigmoid(g)*a*s computed in mgemm act=5 store phase.
//  R8 measured: fusing THIS kernel into J9's store phase is net-negative.)
__global__ __launch_bounds__(256) void combine_cls_k(
    const bf16* __restrict__ v1, const bf16* __restrict__ v2,
    const float* __restrict__ w, const float* __restrict__ bias, float* __restrict__ out)
{
    __shared__ float r0[256], r1[256], r2[256];
    const int b = blockIdx.x;
    const int tid = threadIdx.x;
    const size_t off = (size_t)b * DM;
    float p0 = 0.f, p1 = 0.f, p2 = 0.f;
    #pragma unroll
    for (int i = 0; i < 3; ++i){
        const int c = tid + i * 256;
        const float v = cvt(v1[off + c]) + cvt(v2[off + c]);
        p0 = fmaf(v, w[c],         p0);
        p1 = fmaf(v, w[DM + c],    p1);
        p2 = fmaf(v, w[2*DM + c],  p2);
    }
    r0[tid] = p0; r1[tid] = p1; r2[tid] = p2; __syncthreads();
    for (int s = 128; s > 0; s >>= 1){
        if (tid < s){ r0[tid] += r0[tid + s]; r1[tid] += r1[tid + s]; r2[tid] += r2[tid + s]; }
        __syncthreads();
    }
    if (tid == 0){
        const float l0 = r0[0] + bias[0];
        const float l1 = r1[0] + bias[1];
        const float l2 = r2[0] + bias[2];
        const float mx = fmaxf(l0, fmaxf(l1, l2));
        const float e0 = __expf(l0 - mx), e1 = __expf(l1 - mx), e2 = __expf(l2 - mx);
        const float inv = 1.f / (e0 + e1 + e2);
        out[(size_t)b * 3 + 0] = e0 * inv;
        out[(size_t)b * 3 + 1] = e1 * inv;
        out[(size_t)b * 3 + 2] = e2 * inv;
    }
}

extern "C" void kernel_launch(void* const* d_in, const int* in_sizes, int n_in,
                              void* d_out, int out_size, void* d_ws, size_t ws_size,
                              hipStream_t stream)
{
    const float* text   = (const float*)d_in[0];
    const float* image  = (const float*)d_in[1];
    const float* tl_w   = (const float*)d_in[2];
    const float* tl_b   = (const float*)d_in[3];
    const float* il_w   = (const float*)d_in[4];
    const float* il_b   = (const float*)d_in[5];
    const float* sda_wv = (const float*)d_in[10];
    const float* sda_bv = (const float*)d_in[11];
    const float* sda_wo = (const float*)d_in[12];
    const float* sda_bo = (const float*)d_in[13];
    const float* fda_w1 = (const float*)d_in[14];
    const float* fda_b1 = (const float*)d_in[15];
    const float* bn1_g  = (const float*)d_in[16];
    const float* bn1_b  = (const float*)d_in[17];
    const float* ca_w1  = (const float*)d_in[18];
    const float* ca_w2  = (const float*)d_in[19];
    const float* sa_w   = (const float*)d_in[20];
    const float* sa_b   = (const float*)d_in[21];
    const float* dec_w  = (const float*)d_in[22];
    const float* dec_b  = (const float*)d_in[23];
    const float* sigma  = (const float*)d_in[24];
    const float* fda_wf = (const float*)d_in[25];
    const float* fda_bf = (const float*)d_in[26];
    const float* bn2_g  = (const float*)d_in[27];
    const float* bn2_b  = (const float*)d_in[28];
    const float* dmi_wq = (const float*)d_in[29];
    const float* dmi_bq = (const float*)d_in[30];
    const float* dmi_wk = (const float*)d_in[31];
    const float* dmi_bk = (const float*)d_in[32];
    const float* dmi_wv = (const float*)d_in[33];
    const float* dmi_bv = (const float*)d_in[34];
    const float* tg_w1  = (const float*)d_in[35];
    const float* tg_b1  = (const float*)d_in[36];
    const float* tg_w2  = (const float*)d_in[37];
    const float* tg_b2  = (const float*)d_in[38];
    const float* ig_w1  = (const float*)d_in[39];
    const float* ig_b1  = (const float*)d_in[40];
    const float* ig_w2  = (const float*)d_in[41];
    const float* ig_b2  = (const float*)d_in[42];
    const float* t_scale= (const float*)d_in[43];
    const float* i_scale= (const float*)d_in[44];
    const float* cls_w  = (const float*)d_in[45];
    const float* cls_b  = (const float*)d_in[46];
    float* out = (float*)d_out;

    // ---- workspace (~129 MB) ----
    char* base = (char*)d_ws;
    auto alloc = [&](size_t bytes){ void* p = (void*)base; base += (bytes + 255) & ~(size_t)255; return p; };
    const size_t SLOT = (size_t)NB * DM;
    const size_t W768 = (size_t)768 * 768;
    bf16* tl_wb   = (bf16*)alloc(W768 * 2);
    bf16* il_wb   = (bf16*)alloc(W768 * 2);
    bf16* sda_wvb = (bf16*)alloc((size_t)512 * 768 * 2);
    bf16* sda_wob = (bf16*)alloc((size_t)768 * 512 * 2);
    bf16* fda_wfb = (bf16*)alloc((size_t)768 * 384 * 2);
    // dmi_wqb and dmi_wkb MUST stay adjacent: together they form Wqk (1536x768)
    // for the merged J5 jobs. (All preceding alloc sizes are 256-multiples, so
    // alloc introduces no padding between them.)
    bf16* dmi_wqb = (bf16*)alloc(W768 * 2);
    bf16* dmi_wkb = (bf16*)alloc(W768 * 2);
    bf16* dmi_wvb = (bf16*)alloc(W768 * 2);
    bf16* tg_w1b  = (bf16*)alloc(W768 * 2);
    bf16* tg_w2b  = (bf16*)alloc(W768 * 2);
    bf16* ig_w1b  = (bf16*)alloc(W768 * 2);
    bf16* ig_w2b  = (bf16*)alloc(W768 * 2);
    bf16* w1c     = (bf16*)alloc((size_t)384 * 768 * 2);
    float* sac    = (float*)alloc(1536 * 4);
    float* qkb    = (float*)alloc(1536 * 4);                 // [bq; bk] concat
    float* lbuf   = (float*)alloc(2 * NB * 4);               // final denominators [2][NB]
    float* part   = (float*)alloc((size_t)2 * 32 * NB * 4);  // per-chunk partials [2][32][NB], 1 MB
    bf16* SL[8];
    for (int i = 0; i < 8; ++i) SL[i] = (bf16*)alloc(SLOT * 2);  // contiguous: SL[i]+SLOT == SL[i+1]
    bf16* SC1 = (bf16*)alloc((size_t)NB * NB * 2);
    bf16* SC2 = (bf16*)alloc((size_t)NB * NB * 2);

    const float bnscale = 1.0f / sqrtf(1.0f + 1e-5f);
    const float iscale  = 1.0f / sqrtf(768.0f);
    const dim3 blk(256);

    struct JB {
        Jobs jb; int blocks;
        void add(const bf16* A, const bf16* B, bf16* C, int M, int N, int K, int ldA, int ldB,
                 const float* b0, float al, const float* gv, const float* b1, int act, int trans,
                 float* rs = nullptr, const bf16* aux = nullptr, const float* sv = nullptr){
            Job& j = jb.j[jb.nj++];
            j.A=A; j.B=B; j.C=C; j.b0=b0; j.gv=gv; j.b1=b1; j.rs=rs; j.aux=aux; j.sv=sv;
            j.M=M; j.N=N; j.K=K; j.ldA=ldA; j.ldB=ldB; j.act=act; j.trans=trans;
            j.alpha=al; j.blk0=blocks; j.nx=N/128; j.nb=(N/128)*(M/128);
            blocks += (N/128)*(M/128);
        }
    };
    auto launch = [&](JB& b){ mgemm_k<<<dim3(b.blocks), blk, 0, stream>>>(b.jb); };

    // fp32 -> bf16 staging (+ merged conv-weight extract + QK-bias concat)
    CvtDesc cd;
    const float* srcs[NCVT] = {text, image, tl_w, il_w, sda_wv, sda_wo, fda_wf,
                               dmi_wq, dmi_wk, dmi_wv, tg_w1, tg_w2, ig_w1, ig_w2};
    bf16* dsts[NCVT] = {SL[0], SL[1], tl_wb, il_wb, sda_wvb, sda_wob, fda_wfb,
                        dmi_wqb, dmi_wkb, dmi_wvb, tg_w1b, tg_w2b, ig_w1b, ig_w2b};
    int   lens[NCVT] = {(int)SLOT, (int)SLOT, (int)W768, (int)W768, 512*768, 768*512, 768*384,
                        (int)W768, (int)W768, (int)W768, (int)W768, (int)W768, (int)W768, (int)W768};
    for (int i = 0; i < NCVT; ++i){ cd.s[i] = srcs[i]; cd.d[i] = dsts[i]; cd.n[i] = lens[i]; }
    cvt_k<<<dim3((int)(SLOT / 1024), NCVT + 1), blk, 0, stream>>>(cd, fda_w1, sa_w, w1c, sac,
                                                                  dmi_bq, dmi_bk, qkb);

    // J1: t0 = gelu(text@tl^T) -> SL2 ; im0 = gelu(image@il^T) -> SL3
    { JB b{}; b.add(SL[0], tl_wb, SL[2], NB, DM, DM, DM, DM, tl_b, 1.f, nullptr, nullptr, 1, 0);
              b.add(SL[1], il_wb, SL[3], NB, DM, DM, DM, DM, il_b, 1.f, nullptr, nullptr, 1, 0); launch(b); }
    // J2: wv = t0@wv^T -> SL0 (N=512) ; x1 = conv1(im0) -> SL1 (N=384)
    { JB b{}; b.add(SL[2], sda_wvb, SL[0], NB, 512, DM, DM, DM, sda_bv, 1.f, nullptr, nullptr, 0, 0);
              b.add(SL[3], w1c,     SL[1], NB, 384, DM, DM, DM, fda_b1, bnscale, bn1_g, bn1_b, 1, 0); launch(b); }
    // fused FDA tail (in place on SL1)
    fda_fused_k<<<dim3(NB), dim3(128), 0, stream>>>(SL[1], ca_w1, ca_w2, sac, sa_b, dec_w, dec_b, sigma);
    // J34 (batched): t1 = wv@wo^T -> SL4 (K=512) ; im1 = gelu((x4@wf^T+bf)*bn2) -> SL5 (K=384)
    { JB b{}; b.add(SL[0], sda_wob, SL[4], NB, DM, 512, 512, 512, sda_bo, 1.f, nullptr, nullptr, 0, 0);
              b.add(SL[1], fda_wfb, SL[5], NB, DM, 384, 384, 384, fda_bf, bnscale, bn2_g, bn2_b, 1, 0); launch(b); }

    // J5: merged QK (N=1536, Wqk = [wq;wk]) both directions + V^T jobs.
    //   bufT = SL0..SL1 (4096x1536): cols 0-767 = Q_t, 768-1535 = K_t
    //   bufI = SL2..SL3 (4096x1536): cols 0-767 = Q_im, 768-1535 = K_im
    { JB b{};
      b.add(SL[4], dmi_wqb, SL[0], NB, 1536, DM, DM, DM, qkb,    1.f, nullptr, nullptr, 0, 0);
      b.add(SL[5], dmi_wqb, SL[2], NB, 1536, DM, DM, DM, qkb,    1.f, nullptr, nullptr, 0, 0);
      b.add(SL[5], dmi_wvb, SL[6], NB, DM,   DM, DM, DM, dmi_bv, 1.f, nullptr, nullptr, 0, 1);   // V_im^T
      b.add(SL[4], dmi_wvb, SL[7], NB, DM,   DM, DM, DM, dmi_bv, 1.f, nullptr, nullptr, 0, 1);   // V_t^T
      launch(b); }
    // J6: scores (strided Q/K slices, ld=1536) with fused exp + per-block partial row sums
    { JB b{}; b.add(SL[0],       SL[2] + 768, SC1, NB, NB, DM, 1536, 1536, nullptr, iscale, nullptr, nullptr, 4, 0, part);
              b.add(SL[2],       SL[0] + 768, SC2, NB, NB, DM, 1536, 1536, nullptr, iscale, nullptr, nullptr, 4, 0, part + 32 * NB); launch(b); }
    // reduce partials -> lbuf
    denom_k<<<dim3((2 * NB + 255) / 256), blk, 0, stream>>>(part, lbuf);
    // J7: PV split-K=2 x 2 dirs (4 jobs, 768 blocks) on unnormalized exp-scores
    { JB b{};
      b.add(SC1,        SL[6],        SL[0], NB, DM, 2048, NB, NB, nullptr, 1.f, nullptr, nullptr, 0, 0);
      b.add(SC1 + 2048, SL[6] + 2048, SL[1], NB, DM, 2048, NB, NB, nullptr, 1.f, nullptr, nullptr, 0, 0);
      b.add(SC2,        SL[7],        SL[2], NB, DM, 2048, NB, NB, nullptr, 1.f, nullptr, nullptr, 0, 0);
      b.add(SC2 + 2048, SL[7] + 2048, SL[3], NB, DM, 2048, NB, NB, nullptr, 1.f, nullptr, nullptr, 0, 0);
      launch(b); }
    // a1 = (SL0+SL1)/l1 -> SL4 ; a2 = (SL2+SL3)/l2 -> SL5
    reduce2_k<<<dim3((int)(SLOT / 2048)), blk, 0, stream>>>(SL[0], SL[1], SL[4], lbuf,
                                                           SL[2], SL[3], SL[5], lbuf + NB);
    // J8: gate hidden (relu)
    { JB b{}; b.add(SL[4], tg_w1b, SL[0], NB, DM, DM, DM, DM, tg_b1, 1.f, nullptr, nullptr, 3, 0);
              b.add(SL[5], ig_w1b, SL[1], NB, DM, DM, DM, DM, ig_b1, 1.f, nullptr, nullptr, 3, 0); launch(b); }
    // J9: gate out + fused combine (act=5): v = sigmoid(logit)*a*scale
    { JB b{}; b.add(SL[0], tg_w2b, SL[3], NB, DM, DM, DM, DM, tg_b2, 1.f, nullptr, nullptr, 5, 0, nullptr, SL[4], t_scale);
              b.add(SL[1], ig_w2b, SL[6], NB, DM, DM, DM, DM, ig_b2, 1.f, nullptr, nullptr, 5, 0, nullptr, SL[5], i_scale); launch(b); }
    // slim classifier + softmax
    combine_cls_k<<<dim3(NB), blk, 0, stream>>>(SL[3], SL[6], cls_w, cls_b, out);
}